// Round 3
// baseline (15488.373 us; speedup 1.0000x reference)
//
#include <hip/hip_runtime.h>
#include <hip/hip_fp16.h>
#include <stdint.h>

// LSTM-like scan, T=4096, E=1024, H=1024.
// Phase 1: xpre[t][g*1024+j] = x @ U_g^T + B_g   (fp32 tiled GEMM, stored fp16)
// Phase 2: persistent 64-WG x 512-thread kernel.
//   Lane (row, k) owns ALL 4 gates of `row` over h-chunk [32k, 32k+32):
//     - 64 weight dwords (128 fp16) pinned in VGPRs (loop-carried asm pin)
//     - per step: 16 LDS dwords of packed h, 64 v_dot2, 5-level shfl reduce
//     - k==0 leader does sigmoids, s-update, tanh, publish. ONE barrier/step.
//   h broadcast: tagged dwords ((epoch<<16)|fp16) via agent-scope atomics;
//   wave 0 polls, packs, writes LDS (stride-20 swizzled, double-buffered).

#define T_STEPS 4096
#define HDIM 1024
#define NWG 64

typedef _Float16 half2v __attribute__((ext_vector_type(2)));
typedef uint32_t u32x4 __attribute__((ext_vector_type(4)));

__device__ __forceinline__ float dot2(uint32_t a, uint32_t b, float c) {
#if __has_builtin(__builtin_amdgcn_fdot2)
  return __builtin_amdgcn_fdot2(__builtin_bit_cast(half2v, a),
                                __builtin_bit_cast(half2v, b), c, false);
#else
  half2v av = __builtin_bit_cast(half2v, a);
  half2v bv = __builtin_bit_cast(half2v, b);
  return c + (float)av.x * (float)bv.x + (float)av.y * (float)bv.y;
#endif
}

__device__ __forceinline__ float sigf(float z) { return 1.f / (1.f + __expf(-z)); }

// ---- weight repack: gate-major f32 [4][1024][1024] -> per-lane-packed fp16 ----
// Lane lg = wg*512+tid (wg=lg>>9): row = (wg<<4)+(tid>>5), k = tid&31.
// Lane block = 64 dwords: i = g*16 + ic, covering cols 32k+2*ic, +1.
__global__ __launch_bounds__(256) void convw(const float* __restrict__ w0,
                                             const float* __restrict__ w1,
                                             const float* __restrict__ w2,
                                             const float* __restrict__ w3,
                                             uint32_t* __restrict__ dst) {
  int o = blockIdx.x * 256 + threadIdx.x;  // 0 .. 2M-1 output dwords
  int i = o & 63;
  int lg = o >> 6;
  int wg = lg >> 9, tidl = lg & 511;
  int k = tidl & 31, rloc = tidl >> 5;
  int row = (wg << 4) + rloc;
  int g = i >> 4, ic = i & 15;
  int col = (k << 5) + (ic << 1);
  const float* src = g == 0 ? w0 : g == 1 ? w1 : g == 2 ? w2 : w3;
  float2 v = *(const float2*)(src + (size_t)row * 1024 + col);
  uint32_t dw = (uint32_t)__half_as_ushort(__float2half(v.x)) |
                ((uint32_t)__half_as_ushort(__float2half(v.y)) << 16);
  dst[o] = dw;
}

// ---------------- zero the tagged h broadcast buffers (2 x 1024 dwords) --------
__global__ void zerok(uint32_t* __restrict__ p) {
  int i = blockIdx.x * 256 + threadIdx.x;
  if (i < 2048) p[i] = 0;
}

// ---------------- fp32 GEMM: C[t][n] = x[t][:] . U_g[j][:] + B_g[j] ------------
__global__ __launch_bounds__(256) void gemmk(
    const float* __restrict__ x,
    const float* __restrict__ u0, const float* __restrict__ u1,
    const float* __restrict__ u2, const float* __restrict__ u3,
    const float* __restrict__ b0, const float* __restrict__ b1,
    const float* __restrict__ b2, const float* __restrict__ b3,
    __half* __restrict__ xpre) {
  __shared__ float As[64][33];
  __shared__ float Bs[64][33];
  const int tid = threadIdx.x;
  const int m0 = blockIdx.y * 64;
  const int n0 = blockIdx.x * 64;
  const int g = n0 >> 10;
  const float* Up = g == 0 ? u0 : g == 1 ? u1 : g == 2 ? u2 : u3;
  const float* Bp = g == 0 ? b0 : g == 1 ? b1 : g == 2 ? b2 : b3;
  const int j0 = n0 & 1023;
  const int tx = tid & 15, ty = tid >> 4;
  const int lr = tid >> 3, lc = (tid & 7) << 2;
  float acc[4][4] = {};
  for (int k0 = 0; k0 < 1024; k0 += 32) {
    float4 a0 = *(const float4*)&x[(size_t)(m0 + lr) * 1024 + k0 + lc];
    float4 a1 = *(const float4*)&x[(size_t)(m0 + lr + 32) * 1024 + k0 + lc];
    float4 c0 = *(const float4*)&Up[(size_t)(j0 + lr) * 1024 + k0 + lc];
    float4 c1 = *(const float4*)&Up[(size_t)(j0 + lr + 32) * 1024 + k0 + lc];
    __syncthreads();
    As[lr][lc + 0] = a0.x; As[lr][lc + 1] = a0.y; As[lr][lc + 2] = a0.z; As[lr][lc + 3] = a0.w;
    As[lr + 32][lc + 0] = a1.x; As[lr + 32][lc + 1] = a1.y; As[lr + 32][lc + 2] = a1.z; As[lr + 32][lc + 3] = a1.w;
    Bs[lr][lc + 0] = c0.x; Bs[lr][lc + 1] = c0.y; Bs[lr][lc + 2] = c0.z; Bs[lr][lc + 3] = c0.w;
    Bs[lr + 32][lc + 0] = c1.x; Bs[lr + 32][lc + 1] = c1.y; Bs[lr + 32][lc + 2] = c1.z; Bs[lr + 32][lc + 3] = c1.w;
    __syncthreads();
#pragma unroll
    for (int k = 0; k < 32; ++k) {
      float a0v = As[ty * 4 + 0][k], a1v = As[ty * 4 + 1][k];
      float a2v = As[ty * 4 + 2][k], a3v = As[ty * 4 + 3][k];
      float b0v = Bs[tx * 4 + 0][k], b1v = Bs[tx * 4 + 1][k];
      float b2v = Bs[tx * 4 + 2][k], b3v = Bs[tx * 4 + 3][k];
      acc[0][0] += a0v * b0v; acc[0][1] += a0v * b1v; acc[0][2] += a0v * b2v; acc[0][3] += a0v * b3v;
      acc[1][0] += a1v * b0v; acc[1][1] += a1v * b1v; acc[1][2] += a1v * b2v; acc[1][3] += a1v * b3v;
      acc[2][0] += a2v * b0v; acc[2][1] += a2v * b1v; acc[2][2] += a2v * b2v; acc[2][3] += a2v * b3v;
      acc[3][0] += a3v * b0v; acc[3][1] += a3v * b1v; acc[3][2] += a3v * b2v; acc[3][3] += a3v * b3v;
    }
  }
#pragma unroll
  for (int i = 0; i < 4; ++i) {
    size_t rowi = (size_t)(m0 + ty * 4 + i);
#pragma unroll
    for (int j = 0; j < 4; ++j) {
      int jj = j0 + tx * 4 + j;
      float v = acc[i][j] + Bp[jj];
      xpre[rowi * 4096 + n0 + tx * 4 + j] = __float2half(v);
    }
  }
}

// ---------------- persistent recurrence kernel --------------------------------
__global__ __launch_bounds__(512, 2) void rnnk(
    const uint32_t* __restrict__ wpack,  // [64][512][64] dwords, per-lane packed
    const __half* __restrict__ xpre,     // [4096][4096] fp16, gate-major
    uint32_t* tagged,                    // [2][1024] tagged h dwords
    float* __restrict__ out) {           // [4096][1024] f32
  // packed h dword p stored at hl[buf][20*(p>>4) + (p&15)] (stride-20 swizzle)
  __shared__ uint32_t hl[2][640];
  const int wg = blockIdx.x;
  const int tid = threadIdx.x;
  const int wave = tid >> 6, lane = tid & 63;
  const int k = tid & 31;           // h-chunk index
  const int rloc = tid >> 5;        // 0..15
  const int row = (wg << 4) + rloc; // 0..1023
  const bool w0 = (wave == 0);
  const bool leader = (k == 0);

  // ---- load this lane's 64 weight dwords (4 gates x 16) ----
  u32x4 wv[16];
  {
    const u32x4* wp = reinterpret_cast<const u32x4*>(wpack) +
                      (((size_t)wg << 9) + (size_t)tid) * 16;
#pragma unroll
    for (int i = 0; i < 16; ++i) wv[i] = wp[i];
  }

  float s = 0.f;  // cell state (leader lanes only)

  for (int t = 0; t < T_STEPS; ++t) {
    // loop-carried pin: forces wv resident in VGPRs across iterations
#pragma unroll
    for (int i = 0; i < 16; ++i) asm volatile("" : "+v"(wv[i]));

    // leaders prefetch the 4 gate xpre values (gate-major, 2B each)
    float xf = 0.f, xc = 0.f, xg = 0.f, xq = 0.f;
    if (leader) {
      const __half* xp = xpre + ((size_t)t << 12) + row;
      xf = __half2float(xp[0]);
      xc = __half2float(xp[1024]);
      xg = __half2float(xp[2048]);
      xq = __half2float(xp[3072]);
    }

    const int buf = t & 1;
    // --- wave 0: poll h_{t-1} (16 tagged dwords/lane), pack into LDS ---
    if (w0) {
      const unsigned long long* pp =
          reinterpret_cast<const unsigned long long*>(tagged + (buf << 10)) +
          (lane << 3);
      const uint32_t tg = (uint32_t)t;
      unsigned long long v[8];
      bool ok;
      do {
#pragma unroll
        for (int j = 0; j < 8; ++j)
          v[j] = __hip_atomic_load(pp + j, __ATOMIC_RELAXED, __HIP_MEMORY_SCOPE_AGENT);
        ok = true;
#pragma unroll
        for (int j = 0; j < 8; ++j)
          ok = ok && (((uint32_t)(v[j] >> 16) & 0xffffu) == tg) &&
               ((uint32_t)(v[j] >> 48) == tg);
      } while (!ok);
      uint32_t pk[8];
#pragma unroll
      for (int j = 0; j < 8; ++j)
        pk[j] = (uint32_t)(v[j] & 0xffffu) | (((uint32_t)(v[j] >> 32) & 0xffffu) << 16);
      // p = 8*lane + j -> dst dword = 20*(lane>>1) + 8*(lane&1) + j
      uint32_t* dst = &hl[buf][20 * (lane >> 1) + ((lane & 1) << 3)];
      u32x4 wA, wB;
      wA.x = pk[0]; wA.y = pk[1]; wA.z = pk[2]; wA.w = pk[3];
      wB.x = pk[4]; wB.y = pk[5]; wB.z = pk[6]; wB.w = pk[7];
      *reinterpret_cast<u32x4*>(dst) = wA;
      *reinterpret_cast<u32x4*>(dst + 4) = wB;
    }
    __syncthreads();  // hl[buf] ready (single barrier per step)

    // --- 4 gates x 64 MACs over this lane's 32-element h chunk ---
    float a0 = 0.f, a1 = 0.f, a2 = 0.f, a3 = 0.f;
    const uint32_t* hb = &hl[buf][20 * k];
#pragma unroll
    for (int m = 0; m < 4; ++m) {
      u32x4 h4 = *reinterpret_cast<const u32x4*>(hb + (m << 2));
      a0 = dot2(wv[m].x, h4.x, a0);
      a0 = dot2(wv[m].y, h4.y, a0);
      a0 = dot2(wv[m].z, h4.z, a0);
      a0 = dot2(wv[m].w, h4.w, a0);
      a1 = dot2(wv[4 + m].x, h4.x, a1);
      a1 = dot2(wv[4 + m].y, h4.y, a1);
      a1 = dot2(wv[4 + m].z, h4.z, a1);
      a1 = dot2(wv[4 + m].w, h4.w, a1);
      a2 = dot2(wv[8 + m].x, h4.x, a2);
      a2 = dot2(wv[8 + m].y, h4.y, a2);
      a2 = dot2(wv[8 + m].z, h4.z, a2);
      a2 = dot2(wv[8 + m].w, h4.w, a2);
      a3 = dot2(wv[12 + m].x, h4.x, a3);
      a3 = dot2(wv[12 + m].y, h4.y, a3);
      a3 = dot2(wv[12 + m].z, h4.z, a3);
      a3 = dot2(wv[12 + m].w, h4.w, a3);
    }
    // --- reduce across the 32 chunk-lanes of this row (stays in 32-lane half) ---
#pragma unroll
    for (int mk = 1; mk <= 16; mk <<= 1) {
      a0 += __shfl_xor(a0, mk);
      a1 += __shfl_xor(a1, mk);
      a2 += __shfl_xor(a2, mk);
      a3 += __shfl_xor(a3, mk);
    }

    // --- leader epilogue: gates, s-update, h, publish ---
    if (leader) {
      float f = sigf(a0 + xf);
      float cc = sigf(a1 + xc);
      float gg = sigf(a2 + xg);
      float q = sigf(a3 + xq);
      s = f * s + gg * cc;
      float e2 = __expf(2.f * s);  // s >= 0 always; inf -> th = 1
      float th = 1.f - 2.f / (e2 + 1.f);
      float h = th * q;
      out[(size_t)t * HDIM + row] = h;
      uint32_t dw = ((uint32_t)(t + 1) << 16) |
                    (uint32_t)__half_as_ushort(__float2half(h));
      __hip_atomic_store(&tagged[(((t + 1) & 1) << 10) + row], dw,
                         __ATOMIC_RELAXED, __HIP_MEMORY_SCOPE_AGENT);
    }
    // no trailing barrier: wave0's next write targets hl[buf^1], and its poll
    // for t+1 can only succeed after every wave here published t+1 (i.e. has
    // finished reading hl[buf]).
  }
}

extern "C" void kernel_launch(void* const* d_in, const int* in_sizes, int n_in,
                              void* d_out, int out_size, void* d_ws, size_t ws_size,
                              hipStream_t stream) {
  const float* x  = (const float*)d_in[0];
  const float* Uf = (const float*)d_in[1];
  const float* Wf = (const float*)d_in[2];
  const float* Bf = (const float*)d_in[3];
  const float* Ug = (const float*)d_in[4];
  const float* Wg = (const float*)d_in[5];
  const float* Bg = (const float*)d_in[6];
  const float* Uq = (const float*)d_in[7];
  const float* Wq = (const float*)d_in[8];
  const float* Bq = (const float*)d_in[9];
  const float* U  = (const float*)d_in[10];
  const float* W  = (const float*)d_in[11];
  const float* B  = (const float*)d_in[12];
  float* out = (float*)d_out;

  // ws layout: [0,32MB) xpre fp16 [4096][4096]; [32MB,40MB) wpack 2M dwords;
  // [40MB,+8KB) tagged h dwords [2][1024].
  char* ws = (char*)d_ws;
  __half* xpre = (__half*)ws;
  uint32_t* wpack = (uint32_t*)(ws + (size_t)32 * 1024 * 1024);
  uint32_t* tagged = (uint32_t*)(ws + (size_t)40 * 1024 * 1024);

  // gate order everywhere: 0=f(Uf,Wf,Bf) 1=c(U,W,B) 2=g(Ug,Wg,Bg) 3=q(Uq,Wq,Bq)
  convw<<<8192, 256, 0, stream>>>(Wf, W, Wg, Wq, wpack);
  zerok<<<8, 256, 0, stream>>>(tagged);
  gemmk<<<dim3(64, 64), 256, 0, stream>>>(x, Uf, U, Ug, Uq, Bf, B, Bg, Bq, xpre);
  rnnk<<<NWG, 512, 0, stream>>>(wpack, xpre, tagged, out);
}